// Round 25
// baseline (158.237 us; speedup 1.0000x reference)
//
#include <hip/hip_runtime.h>

#define BB   8
#define CIN  96
#define DIN  192
#define HH   64
#define WW   64
#define LL   4096
#define KK   4
#define COUT 96
#define SS   128  // scan segments
#define LC   32   // segment length = LL/SS

#define LOG2E 1.4426950408889634f
#define LN2   0.6931471805599453f

typedef unsigned short bf16t;
typedef float f32x2 __attribute__((ext_vector_type(2)));
typedef float f32x4 __attribute__((ext_vector_type(4)));
typedef short bf16x8s __attribute__((ext_vector_type(8)));

__device__ __forceinline__ f32x2 pkfma(f32x2 a, f32x2 b, f32x2 c) {
#if __has_builtin(__builtin_elementwise_fma)
  return __builtin_elementwise_fma(a, b, c);
#else
  f32x2 r;
  r[0] = fmaf(a[0], b[0], c[0]);
  r[1] = fmaf(a[1], b[1], c[1]);
  return r;
#endif
}

__device__ __forceinline__ float exp2fast(float x) { return __builtin_amdgcn_exp2f(x); }
__device__ __forceinline__ float log2fast(float x) { return __builtin_amdgcn_logf(x); }
__device__ __forceinline__ float sigf(float x) { return 1.0f / (1.0f + __expf(-x)); }
__device__ __forceinline__ int trp(int p) { return ((p & 63) << 6) | (p >> 6); }
__device__ __forceinline__ int pix_of(int k, int l) {
  if (k == 0) return l;
  if (k == 1) return trp(l);
  if (k == 2) return LL - 1 - l;
  return trp(LL - 1 - l);
}
__device__ __forceinline__ float b2f(bf16t v) {
  return __uint_as_float((unsigned)v << 16);
}
__device__ __forceinline__ bf16t f2b(float f) {  // round-to-nearest-even
  unsigned u = __float_as_uint(f);
  return (bf16t)((u + 0x7FFFu + ((u >> 16) & 1u)) >> 16);
}

// ---------------------------------------------------------------------------
// in_proj via MFMA bf16: xz[o,p] = sum_c W[o,c] x[c,p].
// ---------------------------------------------------------------------------
__global__ __launch_bounds__(256) void gemm_in_mfma_k(const float* __restrict__ x,
                                                      const bf16t* __restrict__ Wb,
                                                      bf16t* __restrict__ out) {
  __shared__ bf16t ldsB[32 * 104];  // [px][c] bf16, pad 104
  const int tid = threadIdx.x;
  const int b = blockIdx.z;
  const int p0 = blockIdx.x * 32;
  for (int idx = tid; idx < CIN * 32; idx += 256) {
    int c = idx >> 5, px = idx & 31;
    ldsB[px * 104 + c] = f2b(x[((size_t)b * CIN + c) * LL + p0 + px]);
  }
  __syncthreads();
  const int wave = tid >> 6, lane = tid & 63;
  const int lm = lane & 15, kc = lane >> 4;
  bf16x8s bfrag[2][3];
#pragma unroll
  for (int nf = 0; nf < 2; ++nf)
#pragma unroll
    for (int ks = 0; ks < 3; ++ks)
      bfrag[nf][ks] = *(const bf16x8s*)&ldsB[(nf * 16 + lm) * 104 + ks * 32 + kc * 8];
  bf16t* ob = out + (size_t)b * 384 * LL + p0;
#pragma unroll
  for (int mti = 0; mti < 6; ++mti) {
    const int o0 = (wave * 6 + mti) * 16;
    bf16x8s afrag[3];
#pragma unroll
    for (int ks = 0; ks < 3; ++ks)
      afrag[ks] = *(const bf16x8s*)&Wb[(size_t)(o0 + lm) * CIN + ks * 32 + kc * 8];
    f32x4 acc0 = {0.f, 0.f, 0.f, 0.f};
    f32x4 acc1 = {0.f, 0.f, 0.f, 0.f};
#pragma unroll
    for (int ks = 0; ks < 3; ++ks) {
      acc0 = __builtin_amdgcn_mfma_f32_16x16x32_bf16(afrag[ks], bfrag[0][ks], acc0, 0, 0, 0);
      acc1 = __builtin_amdgcn_mfma_f32_16x16x32_bf16(afrag[ks], bfrag[1][ks], acc1, 0, 0, 0);
    }
#pragma unroll
    for (int r = 0; r < 4; ++r) {
      ob[(size_t)(o0 + kc * 4 + r) * LL + lm]      = f2b(acc0[r]);
      ob[(size_t)(o0 + kc * 4 + r) * LL + 16 + lm] = f2b(acc1[r]);
    }
  }
}

// ---------------------------------------------------------------------------
// FUSED LayerNorm*silu(z) + out_proj MFMA (split-precision weights).
// ---------------------------------------------------------------------------
__global__ __launch_bounds__(384) void ln_gemm_out_k(const bf16t* __restrict__ ymT,
                                                     const bf16t* __restrict__ ymT2,
                                                     const bf16t* __restrict__ xz,
                                                     const float* __restrict__ gamma,
                                                     const float* __restrict__ beta,
                                                     const bf16t* __restrict__ Wh,
                                                     const bf16t* __restrict__ Wl,
                                                     float* __restrict__ out) {
  __shared__ bf16t ldsB[64 * 200];  // [px][c] bf16, 25.6 KB
  __shared__ float sS[6][64], sQ[6][64];
  const int tid = threadIdx.x;
  const int b = blockIdx.z;
  const int h = blockIdx.x;
  const int p0 = h * 64;
  const bf16t* ymb = ymT + (size_t)b * (384 * (size_t)LL);  // xz overlay
  for (int idx = tid; idx < 64 * DIN; idx += 384) {
    int pp = idx / DIN, dd = idx % DIN;
    float v = b2f(ymb[(size_t)(p0 + pp) * DIN + dd]) +
              b2f(ymT2[((size_t)b * LL + pp * 64 + h) * DIN + dd]);
    ldsB[pp * 200 + dd] = f2b(v);
  }
  __syncthreads();
  const int px = tid & 63, g = tid >> 6;  // g in [0,6)
  float sum = 0.0f, ss = 0.0f;
  for (int dd = g * 32; dd < g * 32 + 32; ++dd) {
    float v = b2f(ldsB[px * 200 + dd]);
    sum += v;
    ss = fmaf(v, v, ss);
  }
  sS[g][px] = sum;
  sQ[g][px] = ss;
  __syncthreads();
  sum = 0.0f; ss = 0.0f;
#pragma unroll
  for (int gg = 0; gg < 6; ++gg) { sum += sS[gg][px]; ss += sQ[gg][px]; }
  const float mu = sum * (1.0f / DIN);
  float var = ss * (1.0f / DIN) - mu * mu;
  const float rstd = rsqrtf(fmaxf(var, 0.0f) + 1e-5f);
  const bf16t* zb = xz + ((size_t)b * 384 + DIN) * LL + p0 + px;
  for (int dd = g * 32; dd < g * 32 + 32; ++dd) {
    float v = b2f(ldsB[px * 200 + dd]);
    float z = b2f(zb[(size_t)dd * LL]);
    float tn = fmaf((v - mu) * rstd, gamma[dd], beta[dd]);
    ldsB[px * 200 + dd] = f2b(tn * (z * sigf(z)));
  }
  __syncthreads();
  const int wave = tid / 64, lane = tid & 63;
  const int lm = lane & 15, kc = lane >> 4;
  const int o0 = wave * 16;
  bf16x8s ah[6], al[6];
#pragma unroll
  for (int ks = 0; ks < 6; ++ks) {
    ah[ks] = *(const bf16x8s*)&Wh[(size_t)(o0 + lm) * DIN + ks * 32 + kc * 8];
    al[ks] = *(const bf16x8s*)&Wl[(size_t)(o0 + lm) * DIN + ks * 32 + kc * 8];
  }
  float* ob = out + (size_t)b * COUT * LL + p0;
#pragma unroll
  for (int nf = 0; nf < 4; ++nf) {
    f32x4 acc = {0.f, 0.f, 0.f, 0.f};
#pragma unroll
    for (int ks = 0; ks < 6; ++ks) {
      bf16x8s bfr = *(const bf16x8s*)&ldsB[(nf * 16 + lm) * 200 + ks * 32 + kc * 8];
      acc = __builtin_amdgcn_mfma_f32_16x16x32_bf16(ah[ks], bfr, acc, 0, 0, 0);
      acc = __builtin_amdgcn_mfma_f32_16x16x32_bf16(al[ks], bfr, acc, 0, 0, 0);
    }
#pragma unroll
    for (int r = 0; r < 4; ++r)
      ob[(size_t)(o0 + kc * 4 + r) * LL + nf * 16 + lm] = acc[r];
  }
}

// ---------------------------------------------------------------------------
// PriorToWeights MLP -> Wg.  Block 0: xpw -> split bf16 pair (32x192).
// Block 1: ipw -> bf16. Block 2: opw -> split bf16 pair.
// ---------------------------------------------------------------------------
__global__ __launch_bounds__(256) void p2w_k(const float* __restrict__ prior,
                                             const float* __restrict__ alpha,
                                             const float* __restrict__ w1,
                                             const float* __restrict__ b1,
                                             const float* __restrict__ bnw,
                                             const float* __restrict__ bnb,
                                             const float* __restrict__ bnm,
                                             const float* __restrict__ bnv,
                                             const float* __restrict__ w2,
                                             const float* __restrict__ b2,
                                             const float* __restrict__ xpw,
                                             const float* __restrict__ ipw,
                                             const float* __restrict__ opw,
                                             bf16t* __restrict__ xpwbh,
                                             bf16t* __restrict__ xpwbl,
                                             bf16t* __restrict__ ipwb,
                                             bf16t* __restrict__ opwbh,
                                             bf16t* __restrict__ opwbl,
                                             float* __restrict__ Wg) {
  if (blockIdx.x == 0) {
    for (int idx = threadIdx.x; idx < 32 * DIN; idx += 256) {
      float w = xpw[idx];
      bf16t hi = f2b(w);
      xpwbh[idx] = hi;
      xpwbl[idx] = f2b(w - b2f(hi));
    }
  }
  if (blockIdx.x == 1) {
    for (int idx = threadIdx.x; idx < 384 * CIN; idx += 256)
      ipwb[idx] = f2b(ipw[idx]);
  }
  if (blockIdx.x == 2) {
    for (int idx = threadIdx.x; idx < COUT * DIN; idx += 256) {
      float w = opw[idx];
      bf16t hi = f2b(w);
      opwbh[idx] = hi;
      opwbl[idx] = f2b(w - b2f(hi));
    }
  }
  int idx = blockIdx.x * 256 + threadIdx.x;
  int p = idx & (LL - 1);
  int b = idx >> 12;
  float pr[4];
#pragma unroll
  for (int c = 0; c < 4; ++c) pr[c] = prior[((size_t)b * 4 + c) * LL + p];
  float s = sigf(alpha[0]);
  float g2[4];
#pragma unroll
  for (int j = 0; j < 4; ++j) g2[j] = b2[j];
  for (int o = 0; o < 32; ++o) {
    float g = b1[o];
#pragma unroll
    for (int c = 0; c < 4; ++c) g = fmaf(pr[c], w1[o * 4 + c], g);
    g = (g - bnm[o]) * rsqrtf(bnv[o] + 1e-5f) * bnw[o] + bnb[o];
    g = fmaxf(g, 0.0f);
#pragma unroll
    for (int j = 0; j < 4; ++j) g2[j] = fmaf(g, w2[j * 32 + o], g2[j]);
  }
#pragma unroll
  for (int j = 0; j < 4; ++j)
    Wg[((size_t)b * 4 + j) * LL + p] = 1.0f + s * (sigf(g2[j]) - 1.0f);
}

// ---------------------------------------------------------------------------
// FUSED conv + x_proj(MFMA): conv+SiLU -> bf16 LDS B-tile; xcT copy; x_proj
// via split-precision MFMA; projS written as ONE float4 per lane (the 4 acc
// rows share k and have consecutive c). Block = 64-px row tile, 512 threads.
// ---------------------------------------------------------------------------
__global__ __launch_bounds__(512) void convproj_k(const bf16t* __restrict__ xz,
                                                  const float* __restrict__ cw,
                                                  const float* __restrict__ cb,
                                                  const bf16t* __restrict__ Wh,
                                                  const bf16t* __restrict__ Wl,
                                                  bf16t* __restrict__ xcT,
                                                  float* __restrict__ projS) {
  __shared__ bf16t sXb[64 * 200];  // [px][dd] bf16, 25.6 KB
  const int tid = threadIdx.x;
  const int b = blockIdx.y;
  const int h = blockIdx.x;
  // Phase A: conv + bias + SiLU (4 consecutive px per iter) -> sXb[px][dd]
  for (int idx = tid; idx < DIN * 16; idx += 512) {
    int dd = idx >> 4, pq = idx & 15;
    int w0 = pq * 4;
    const bf16t* base = xz + ((size_t)b * 384 + dd) * LL + h * 64 + w0;
    const float* wp = cw + dd * 9;
    float bv = cb[dd];
    f32x2 s01 = {bv, bv}, s23 = {bv, bv};
#pragma unroll
    for (int dh = -1; dh <= 1; ++dh) {
      int hh = h + dh;
      if (hh < 0 || hh >= HH) continue;
      const bf16t* row = base + dh * 64;
      ushort4 cmu = *(const ushort4*)row;
      float cmx = b2f(cmu.x), cmy = b2f(cmu.y), cmz = b2f(cmu.z), cmw = b2f(cmu.w);
      float lf = (w0 > 0)  ? b2f(row[-1]) : 0.0f;
      float rt = (w0 < 60) ? b2f(row[4])  : 0.0f;
      float c0 = wp[(dh + 1) * 3], c1 = wp[(dh + 1) * 3 + 1], c2 = wp[(dh + 1) * 3 + 2];
      s01 = pkfma((f32x2){lf,  cmx}, (f32x2){c0, c0}, s01);
      s01 = pkfma((f32x2){cmx, cmy}, (f32x2){c1, c1}, s01);
      s01 = pkfma((f32x2){cmy, cmz}, (f32x2){c2, c2}, s01);
      s23 = pkfma((f32x2){cmy, cmz}, (f32x2){c0, c0}, s23);
      s23 = pkfma((f32x2){cmz, cmw}, (f32x2){c1, c1}, s23);
      s23 = pkfma((f32x2){cmw, rt},  (f32x2){c2, c2}, s23);
    }
    float v0 = s01[0], v1 = s01[1], v2 = s23[0], v3 = s23[1];
    sXb[(w0 + 0) * 200 + dd] = f2b(v0 * sigf(v0));
    sXb[(w0 + 1) * 200 + dd] = f2b(v1 * sigf(v1));
    sXb[(w0 + 2) * 200 + dd] = f2b(v2 * sigf(v2));
    sXb[(w0 + 3) * 200 + dd] = f2b(v3 * sigf(v3));
  }
  __syncthreads();
  // Phase B: xcT copy (coalesced over dd, 8 B chunks)
  for (int idx = tid; idx < 64 * (DIN / 4); idx += 512) {
    int pp = idx / 48, dq = idx % 48;
    *(ushort4*)&xcT[((size_t)b * LL + h * 64 + pp) * DIN + dq * 4] =
        *(const ushort4*)&sXb[pp * 200 + dq * 4];
  }
  // Phase C: x_proj MFMA. wave -> (mti = w>>2, nf = w&3)
  const int wave = tid >> 6, lane = tid & 63;
  const int lm = lane & 15, kc = lane >> 4;
  const int mti = wave >> 2, nf = wave & 3;
  bf16x8s ah[6], al[6], bfr[6];
#pragma unroll
  for (int ks = 0; ks < 6; ++ks) {
    ah[ks] = *(const bf16x8s*)&Wh[(size_t)(mti * 16 + lm) * DIN + ks * 32 + kc * 8];
    al[ks] = *(const bf16x8s*)&Wl[(size_t)(mti * 16 + lm) * DIN + ks * 32 + kc * 8];
    bfr[ks] = *(const bf16x8s*)&sXb[(nf * 16 + lm) * 200 + ks * 32 + kc * 8];
  }
  f32x4 acc = {0.f, 0.f, 0.f, 0.f};
#pragma unroll
  for (int ks = 0; ks < 6; ++ks) {
    acc = __builtin_amdgcn_mfma_f32_16x16x32_bf16(ah[ks], bfr[ks], acc, 0, 0, 0);
    acc = __builtin_amdgcn_mfma_f32_16x16x32_bf16(al[ks], bfr[ks], acc, 0, 0, 0);
  }
  // Phase D: ONE float4 store per lane. Rows o = obase..obase+3 share k and
  // have consecutive c (obase multiple of 4).
  const int obase = mti * 16 + kc * 4;
  const int k = obase >> 3, c0 = obase & 7;
  const int px = nf * 16 + lm;
  const int p = h * 64 + px;
  int l;
  if (k == 0) l = p;
  else if (k == 1) l = trp(p);
  else if (k == 2) l = LL - 1 - p;
  else l = LL - 1 - trp(p);
  *(float4*)&projS[(((size_t)b * KK + k) * LL + l) * 8 + c0] =
      make_float4(acc[0], acc[1], acc[2], acc[3]);
}

// ---------------------------------------------------------------------------
// Scan pass 1 (PAIRED): xcT bf16; carries f32.
// ---------------------------------------------------------------------------
__global__ __launch_bounds__(192) void scan_part_k(const bf16t* __restrict__ xcT,
                                                   const float* __restrict__ projS,
                                                   const float* __restrict__ dtw,
                                                   const float* __restrict__ dtb,
                                                   const float* __restrict__ A_logs,
                                                   float* __restrict__ carrP,
                                                   float* __restrict__ carrH) {
  const int s = blockIdx.x, kp = blockIdx.y, b = blockIdx.z;
  const int d = threadIdx.x;
  const int kA = kp, kB = kp + 2;
  const int s2 = SS - 1 - s;
  const int kdA = kA * DIN + d, kdB = kB * DIN + d;
  float wrA[6], wrB[6];
#pragma unroll
  for (int r = 0; r < 6; ++r) { wrA[r] = dtw[kdA * 6 + r]; wrB[r] = dtw[kdB * 6 + r]; }
  const float biasA = dtb[kdA], biasB = dtb[kdB];
  const float AaA = -__expf(A_logs[kdA]), AaB = -__expf(A_logs[kdB]);
  const int l0 = s * LC;
  const int p0 = pix_of(kA, l0);
  const int dp = pix_of(kA, l0 + 1) - p0;
  const bf16t* xp = xcT + ((size_t)b * LL + p0) * DIN + d;
  const long xstep = (long)dp * DIN;
  const float* prA = projS + (((size_t)b * KK + kA) * LL + l0) * 8;
  const float* prB = projS + (((size_t)b * KK + kB) * LL + s2 * LC + (LC - 1)) * 8;
  float PA = 1.0f, HA = 0.0f, PB = 1.0f, HB = 0.0f;
#pragma unroll 2
  for (int j = 0; j < LC; ++j) {
    float4 a0 = *(const float4*)prA;
    float4 a1 = *(const float4*)(prA + 4);
    prA += 8;
    float4 b0 = *(const float4*)prB;
    float4 b1 = *(const float4*)(prB + 4);
    prB -= 8;
    float xv = b2f(*xp);
    xp += xstep;
    {
      float dtr = biasA;
      dtr = fmaf(a0.x, wrA[0], dtr);
      dtr = fmaf(a0.y, wrA[1], dtr);
      dtr = fmaf(a0.z, wrA[2], dtr);
      dtr = fmaf(a0.w, wrA[3], dtr);
      dtr = fmaf(a1.x, wrA[4], dtr);
      dtr = fmaf(a1.y, wrA[5], dtr);
      float e = exp2fast(fminf(dtr, 80.0f) * LOG2E);
      float u = log2fast(1.0f + e);
      float a = exp2fast(u * AaA);
      float dt = u * LN2;
      HA = fmaf(a, HA, dt * a1.z * xv);
      PA *= a;
    }
    {
      float dtr = biasB;
      dtr = fmaf(b0.x, wrB[0], dtr);
      dtr = fmaf(b0.y, wrB[1], dtr);
      dtr = fmaf(b0.z, wrB[2], dtr);
      dtr = fmaf(b0.w, wrB[3], dtr);
      dtr = fmaf(b1.x, wrB[4], dtr);
      dtr = fmaf(b1.y, wrB[5], dtr);
      float e = exp2fast(fminf(dtr, 80.0f) * LOG2E);
      float u = log2fast(1.0f + e);
      float a = exp2fast(u * AaB);
      float dt = u * LN2;
      HB = fmaf(PB, dt * b1.z * xv, HB);
      PB *= a;
    }
  }
  size_t oA = ((size_t)((b * KK + kA) * SS + s)) * DIN + d;
  size_t oB = ((size_t)((b * KK + kB) * SS + s2)) * DIN + d;
  carrP[oA] = PA;
  carrH[oA] = HA;
  carrP[oB] = PB;
  carrH[oB] = HB;
}

// ---------------------------------------------------------------------------
// Scan pass 2: serial combine of SS carries -> per-segment initial state h0
// ---------------------------------------------------------------------------
__global__ __launch_bounds__(192) void scan_fix_k(const float* __restrict__ carrP,
                                                  const float* __restrict__ carrH,
                                                  float* __restrict__ h0) {
  const int k = blockIdx.x, b = blockIdx.y, d = threadIdx.x;
  size_t base = ((size_t)(b * KK + k)) * SS * DIN + d;
  float h = 0.0f;
#pragma unroll 4
  for (int s = 0; s < SS; ++s) {
    h0[base + (size_t)s * DIN] = h;
    h = fmaf(carrP[base + (size_t)s * DIN], h, carrH[base + (size_t)s * DIN]);
  }
}

// ---------------------------------------------------------------------------
// Scan pass 3: apply + gate + paired merge; xcT bf16 in (reg-cached for dir B),
// ymT/ymT2 bf16 out.
// ---------------------------------------------------------------------------
__global__ __launch_bounds__(192) void scan_apply_k(const bf16t* __restrict__ xcT,
                                                    const float* __restrict__ projS,
                                                    const float* __restrict__ Wg,
                                                    const float* __restrict__ h0,
                                                    const float* __restrict__ dtw,
                                                    const float* __restrict__ dtb,
                                                    const float* __restrict__ A_logs,
                                                    const float* __restrict__ Ds,
                                                    bf16t* __restrict__ ymT,
                                                    bf16t* __restrict__ ymT2) {
  const int s = blockIdx.x, kp = blockIdx.y, b = blockIdx.z;
  const int d = threadIdx.x;
  __shared__ float sAcc[LC * DIN];  // 24 KB, column d thread-private
  float xr[LC];                     // register cache of this segment's xv
  {
    const int k = kp, kd = k * DIN + d;
    float wr[6];
#pragma unroll
    for (int r = 0; r < 6; ++r) wr[r] = dtw[kd * 6 + r];
    const float bias = dtb[kd];
    const float Aa = -__expf(A_logs[kd]);
    const float Dv = Ds[kd];
    const int l0 = s * LC;
    const int p0 = pix_of(k, l0);
    const int dp = pix_of(k, l0 + 1) - p0;
    const bf16t* xp = xcT + ((size_t)b * LL + p0) * DIN + d;
    const long xstep = (long)dp * DIN;
    const float* pr = projS + (((size_t)b * KK + k) * LL + l0) * 8;
    const float* wg = Wg + ((size_t)b * KK + k) * LL + l0;
    float h = h0[((size_t)((b * KK + k) * SS + s)) * DIN + d];
#pragma unroll
    for (int j = 0; j < LC; ++j) {
      float4 q0 = *(const float4*)pr;
      float4 q1 = *(const float4*)(pr + 4);
      pr += 8;
      float xv = b2f(*xp);
      xp += xstep;
      xr[j] = xv;
      float dtr = bias;
      dtr = fmaf(q0.x, wr[0], dtr);
      dtr = fmaf(q0.y, wr[1], dtr);
      dtr = fmaf(q0.z, wr[2], dtr);
      dtr = fmaf(q0.w, wr[3], dtr);
      dtr = fmaf(q1.x, wr[4], dtr);
      dtr = fmaf(q1.y, wr[5], dtr);
      float e = exp2fast(fminf(dtr, 80.0f) * LOG2E);
      float u = log2fast(1.0f + e);
      float a = exp2fast(u * Aa);
      float dt = u * LN2;
      h = fmaf(a, h, dt * q1.z * xv);
      sAcc[j * DIN + d] = fmaf(h, q1.w, Dv * xv) * wg[j];
    }
  }
  {
    const int k = kp + 2, kd = k * DIN + d;
    const int s2 = SS - 1 - s;
    float wr[6];
#pragma unroll
    for (int r = 0; r < 6; ++r) wr[r] = dtw[kd * 6 + r];
    const float bias = dtb[kd];
    const float Aa = -__expf(A_logs[kd]);
    const float Dv = Ds[kd];
    const int l0 = s2 * LC;
    const float* pr = projS + (((size_t)b * KK + k) * LL + l0) * 8;
    const float* wg = Wg + ((size_t)b * KK + k) * LL + l0;
    float h = h0[((size_t)((b * KK + k) * SS + s2)) * DIN + d];
#pragma unroll
    for (int j = 0; j < LC; ++j) {
      float4 q0 = *(const float4*)pr;
      float4 q1 = *(const float4*)(pr + 4);
      pr += 8;
      float xv = xr[LC - 1 - j];   // same pixels, reversed (static index)
      float dtr = bias;
      dtr = fmaf(q0.x, wr[0], dtr);
      dtr = fmaf(q0.y, wr[1], dtr);
      dtr = fmaf(q0.z, wr[2], dtr);
      dtr = fmaf(q0.w, wr[3], dtr);
      dtr = fmaf(q1.x, wr[4], dtr);
      dtr = fmaf(q1.y, wr[5], dtr);
      float e = exp2fast(fminf(dtr, 80.0f) * LOG2E);
      float u = log2fast(1.0f + e);
      float a = exp2fast(u * Aa);
      float dt = u * LN2;
      h = fmaf(a, h, dt * q1.z * xv);
      float y = fmaf(h, q1.w, Dv * xv) * wg[j];
      sAcc[(LC - 1 - j) * DIN + d] += y;
    }
  }
  bf16t* dst;
  if (kp == 0)
    dst = ymT + (size_t)b * (384 * (size_t)LL) + (size_t)(s * LC) * DIN + d;  // xz overlay
  else
    dst = ymT2 + ((size_t)b * LL + s * LC) * DIN + d;
#pragma unroll 4
  for (int j = 0; j < LC; ++j) dst[(size_t)j * DIN] = f2b(sAcc[j * DIN + d]);
}

// ---------------------------------------------------------------------------
extern "C" void kernel_launch(void* const* d_in, const int* in_sizes, int n_in,
                              void* d_out, int out_size, void* d_ws, size_t ws_size,
                              hipStream_t stream) {
  const float* x      = (const float*)d_in[0];
  const float* prior  = (const float*)d_in[1];
  const float* alpha  = (const float*)d_in[2];
  const float* ipw    = (const float*)d_in[3];
  const float* cw     = (const float*)d_in[4];
  const float* cb     = (const float*)d_in[5];
  const float* xpw    = (const float*)d_in[6];
  const float* dtw    = (const float*)d_in[7];
  const float* dtb    = (const float*)d_in[8];
  const float* A_logs = (const float*)d_in[9];
  const float* Ds     = (const float*)d_in[10];
  const float* onw    = (const float*)d_in[11];
  const float* onb    = (const float*)d_in[12];
  const float* opw    = (const float*)d_in[13];
  const float* w1     = (const float*)d_in[14];
  const float* b1     = (const float*)d_in[15];
  const float* bnw    = (const float*)d_in[16];
  const float* bnb    = (const float*)d_in[17];
  const float* bnm    = (const float*)d_in[18];
  const float* bnv    = (const float*)d_in[19];
  const float* w2     = (const float*)d_in[20];
  const float* b2     = (const float*)d_in[21];
  float* out = (float*)d_out;

  char* ws = (char*)d_ws;
  // bf16 intermediates; footprint ends at 64,659,456 B.
  bf16t* xz    = (bf16t*)(ws);              // [B,384,L] bf16  25.2 MB
  bf16t* xcT   = (bf16t*)(ws + 25165824);   // [B,L,192] bf16  12.6 MB
  bf16t* ymT2  = (bf16t*)(ws + 37748736);   // [B,L,192] bf16  12.6 MB
  float* projS = (float*)(ws + 50331648);   // [B,K,L,8] f32    4.2 MB
  float* Wgb   = (float*)(ws + 54525952);   // [B,4,L]          0.5 MB
  float* carrP = (float*)(ws + 55050240);   // [B,K,SS,192]     3.0 MB
  float* carrH = (float*)(ws + 58195968);   // [B,K,SS,192]     3.0 MB
  float* h0b   = (float*)(ws + 61341696);   // [B,K,SS,192]     3.0 MB
  bf16t* xpwbh = (bf16t*)(ws + 64487424);   // [32,192] bf16   12.3 KB
  bf16t* xpwbl = (bf16t*)(ws + 64499712);   // [32,192] bf16   12.3 KB
  bf16t* ipwb  = (bf16t*)(ws + 64512000);   // [384,96] bf16   73.7 KB
  bf16t* opwbh = (bf16t*)(ws + 64585728);   // [96,192] bf16   36.9 KB
  bf16t* opwbl = (bf16t*)(ws + 64622592);   // [96,192] bf16   36.9 KB (ends 64659456)
  bf16t* ymT   = xz;   // overlay: x_ssm half of xz (dead after convproj)

  // 1) prior -> direction gates (+ weight preps in blocks 0,1,2)
  p2w_k<<<(BB * LL) / 256, 256, 0, stream>>>(prior, alpha, w1, b1, bnw, bnb, bnm,
                                             bnv, w2, b2, xpw, ipw, opw, xpwbh,
                                             xpwbl, ipwb, opwbh, opwbl, Wgb);
  // 2) in_proj via MFMA bf16 -> xz bf16
  gemm_in_mfma_k<<<dim3(LL / 32, 1, BB), 256, 0, stream>>>(x, ipwb, xz);
  // 3) fused dwconv+SiLU + x_proj MFMA (float4 projS stores) + xcT copy
  convproj_k<<<dim3(HH, BB), 512, 0, stream>>>(xz, cw, cb, xpwbh, xpwbl, xcT, projS);
  // 4) scan: paired segment carries
  scan_part_k<<<dim3(SS, 2, BB), 192, 0, stream>>>(xcT, projS, dtw, dtb, A_logs,
                                                   carrP, carrH);
  // 5) scan: serial carry combine
  scan_fix_k<<<dim3(KK, BB), 192, 0, stream>>>(carrP, carrH, h0b);
  // 6) scan: apply + gate + paired merge (ymT overlaid on xz x_ssm half)
  scan_apply_k<<<dim3(SS, 2, BB), 192, 0, stream>>>(xcT, projS, Wgb, h0b, dtw, dtb,
                                                    A_logs, Ds, ymT, ymT2);
  // 7) fused LayerNorm*silu(z) + out_proj MFMA -> out f32
  ln_gemm_out_k<<<dim3(LL / 64, 1, BB), 384, 0, stream>>>(ymT, ymT2, xz, onw, onb,
                                                          opwbh, opwbl, out);
}

// Round 26
// 154.333 us; speedup vs baseline: 1.0253x; 1.0253x over previous
//
#include <hip/hip_runtime.h>

#define BB   8
#define CIN  96
#define DIN  192
#define HH   64
#define WW   64
#define LL   4096
#define KK   4
#define COUT 96
#define SS   128  // scan segments
#define LC   32   // segment length = LL/SS

#define LOG2E 1.4426950408889634f
#define LN2   0.6931471805599453f

typedef unsigned short bf16t;
typedef float f32x2 __attribute__((ext_vector_type(2)));
typedef float f32x4 __attribute__((ext_vector_type(4)));
typedef short bf16x8s __attribute__((ext_vector_type(8)));

__device__ __forceinline__ f32x2 pkfma(f32x2 a, f32x2 b, f32x2 c) {
#if __has_builtin(__builtin_elementwise_fma)
  return __builtin_elementwise_fma(a, b, c);
#else
  f32x2 r;
  r[0] = fmaf(a[0], b[0], c[0]);
  r[1] = fmaf(a[1], b[1], c[1]);
  return r;
#endif
}

__device__ __forceinline__ float exp2fast(float x) { return __builtin_amdgcn_exp2f(x); }
__device__ __forceinline__ float log2fast(float x) { return __builtin_amdgcn_logf(x); }
__device__ __forceinline__ float sigf(float x) { return 1.0f / (1.0f + __expf(-x)); }
__device__ __forceinline__ int trp(int p) { return ((p & 63) << 6) | (p >> 6); }
__device__ __forceinline__ int pix_of(int k, int l) {
  if (k == 0) return l;
  if (k == 1) return trp(l);
  if (k == 2) return LL - 1 - l;
  return trp(LL - 1 - l);
}
__device__ __forceinline__ float b2f(bf16t v) {
  return __uint_as_float((unsigned)v << 16);
}
__device__ __forceinline__ bf16t f2b(float f) {  // round-to-nearest-even
  unsigned u = __float_as_uint(f);
  return (bf16t)((u + 0x7FFFu + ((u >> 16) & 1u)) >> 16);
}

// ---------------------------------------------------------------------------
// in_proj via MFMA bf16: xz[o,p] = sum_c W[o,c] x[c,p].
// ---------------------------------------------------------------------------
__global__ __launch_bounds__(256) void gemm_in_mfma_k(const float* __restrict__ x,
                                                      const bf16t* __restrict__ Wb,
                                                      bf16t* __restrict__ out) {
  __shared__ bf16t ldsB[32 * 104];  // [px][c] bf16, pad 104
  const int tid = threadIdx.x;
  const int b = blockIdx.z;
  const int p0 = blockIdx.x * 32;
  for (int idx = tid; idx < CIN * 32; idx += 256) {
    int c = idx >> 5, px = idx & 31;
    ldsB[px * 104 + c] = f2b(x[((size_t)b * CIN + c) * LL + p0 + px]);
  }
  __syncthreads();
  const int wave = tid >> 6, lane = tid & 63;
  const int lm = lane & 15, kc = lane >> 4;
  bf16x8s bfrag[2][3];
#pragma unroll
  for (int nf = 0; nf < 2; ++nf)
#pragma unroll
    for (int ks = 0; ks < 3; ++ks)
      bfrag[nf][ks] = *(const bf16x8s*)&ldsB[(nf * 16 + lm) * 104 + ks * 32 + kc * 8];
  bf16t* ob = out + (size_t)b * 384 * LL + p0;
#pragma unroll
  for (int mti = 0; mti < 6; ++mti) {
    const int o0 = (wave * 6 + mti) * 16;
    bf16x8s afrag[3];
#pragma unroll
    for (int ks = 0; ks < 3; ++ks)
      afrag[ks] = *(const bf16x8s*)&Wb[(size_t)(o0 + lm) * CIN + ks * 32 + kc * 8];
    f32x4 acc0 = {0.f, 0.f, 0.f, 0.f};
    f32x4 acc1 = {0.f, 0.f, 0.f, 0.f};
#pragma unroll
    for (int ks = 0; ks < 3; ++ks) {
      acc0 = __builtin_amdgcn_mfma_f32_16x16x32_bf16(afrag[ks], bfrag[0][ks], acc0, 0, 0, 0);
      acc1 = __builtin_amdgcn_mfma_f32_16x16x32_bf16(afrag[ks], bfrag[1][ks], acc1, 0, 0, 0);
    }
#pragma unroll
    for (int r = 0; r < 4; ++r) {
      ob[(size_t)(o0 + kc * 4 + r) * LL + lm]      = f2b(acc0[r]);
      ob[(size_t)(o0 + kc * 4 + r) * LL + 16 + lm] = f2b(acc1[r]);
    }
  }
}

// ---------------------------------------------------------------------------
// FUSED LayerNorm*silu(z) + out_proj MFMA (split-precision weights).
// ---------------------------------------------------------------------------
__global__ __launch_bounds__(384) void ln_gemm_out_k(const bf16t* __restrict__ ymT,
                                                     const bf16t* __restrict__ ymT2,
                                                     const bf16t* __restrict__ xz,
                                                     const float* __restrict__ gamma,
                                                     const float* __restrict__ beta,
                                                     const bf16t* __restrict__ Wh,
                                                     const bf16t* __restrict__ Wl,
                                                     float* __restrict__ out) {
  __shared__ bf16t ldsB[64 * 200];  // [px][c] bf16, 25.6 KB
  __shared__ float sS[6][64], sQ[6][64];
  const int tid = threadIdx.x;
  const int b = blockIdx.z;
  const int h = blockIdx.x;
  const int p0 = h * 64;
  const bf16t* ymb = ymT + (size_t)b * (384 * (size_t)LL);  // xz overlay
  for (int idx = tid; idx < 64 * DIN; idx += 384) {
    int pp = idx / DIN, dd = idx % DIN;
    float v = b2f(ymb[(size_t)(p0 + pp) * DIN + dd]) +
              b2f(ymT2[((size_t)b * LL + pp * 64 + h) * DIN + dd]);
    ldsB[pp * 200 + dd] = f2b(v);
  }
  __syncthreads();
  const int px = tid & 63, g = tid >> 6;  // g in [0,6)
  float sum = 0.0f, ss = 0.0f;
  for (int dd = g * 32; dd < g * 32 + 32; ++dd) {
    float v = b2f(ldsB[px * 200 + dd]);
    sum += v;
    ss = fmaf(v, v, ss);
  }
  sS[g][px] = sum;
  sQ[g][px] = ss;
  __syncthreads();
  sum = 0.0f; ss = 0.0f;
#pragma unroll
  for (int gg = 0; gg < 6; ++gg) { sum += sS[gg][px]; ss += sQ[gg][px]; }
  const float mu = sum * (1.0f / DIN);
  float var = ss * (1.0f / DIN) - mu * mu;
  const float rstd = rsqrtf(fmaxf(var, 0.0f) + 1e-5f);
  const bf16t* zb = xz + ((size_t)b * 384 + DIN) * LL + p0 + px;
  for (int dd = g * 32; dd < g * 32 + 32; ++dd) {
    float v = b2f(ldsB[px * 200 + dd]);
    float z = b2f(zb[(size_t)dd * LL]);
    float tn = fmaf((v - mu) * rstd, gamma[dd], beta[dd]);
    ldsB[px * 200 + dd] = f2b(tn * (z * sigf(z)));
  }
  __syncthreads();
  const int wave = tid / 64, lane = tid & 63;
  const int lm = lane & 15, kc = lane >> 4;
  const int o0 = wave * 16;
  bf16x8s ah[6], al[6];
#pragma unroll
  for (int ks = 0; ks < 6; ++ks) {
    ah[ks] = *(const bf16x8s*)&Wh[(size_t)(o0 + lm) * DIN + ks * 32 + kc * 8];
    al[ks] = *(const bf16x8s*)&Wl[(size_t)(o0 + lm) * DIN + ks * 32 + kc * 8];
  }
  float* ob = out + (size_t)b * COUT * LL + p0;
#pragma unroll
  for (int nf = 0; nf < 4; ++nf) {
    f32x4 acc = {0.f, 0.f, 0.f, 0.f};
#pragma unroll
    for (int ks = 0; ks < 6; ++ks) {
      bf16x8s bfr = *(const bf16x8s*)&ldsB[(nf * 16 + lm) * 200 + ks * 32 + kc * 8];
      acc = __builtin_amdgcn_mfma_f32_16x16x32_bf16(ah[ks], bfr, acc, 0, 0, 0);
      acc = __builtin_amdgcn_mfma_f32_16x16x32_bf16(al[ks], bfr, acc, 0, 0, 0);
    }
#pragma unroll
    for (int r = 0; r < 4; ++r)
      ob[(size_t)(o0 + kc * 4 + r) * LL + nf * 16 + lm] = acc[r];
  }
}

// ---------------------------------------------------------------------------
// PriorToWeights MLP -> Wg[B,4,L].  Block 0: xpw -> xpwT. Block 1: ipw -> bf16.
// Block 2: opw -> split-precision bf16 pair (hi, lo).
// ---------------------------------------------------------------------------
__global__ __launch_bounds__(256) void p2w_k(const float* __restrict__ prior,
                                             const float* __restrict__ alpha,
                                             const float* __restrict__ w1,
                                             const float* __restrict__ b1,
                                             const float* __restrict__ bnw,
                                             const float* __restrict__ bnb,
                                             const float* __restrict__ bnm,
                                             const float* __restrict__ bnv,
                                             const float* __restrict__ w2,
                                             const float* __restrict__ b2,
                                             const float* __restrict__ xpw,
                                             const float* __restrict__ ipw,
                                             const float* __restrict__ opw,
                                             float* __restrict__ xpwT,
                                             bf16t* __restrict__ ipwb,
                                             bf16t* __restrict__ opwbh,
                                             bf16t* __restrict__ opwbl,
                                             float* __restrict__ Wg) {
  if (blockIdx.x == 0) {
    for (int idx = threadIdx.x; idx < KK * DIN * 8; idx += 256) {
      int kk = idx / (DIN * 8);
      int rem = idx % (DIN * 8);
      int dd = rem >> 3, c = rem & 7;
      xpwT[idx] = xpw[(kk * 8 + c) * DIN + dd];
    }
  }
  if (blockIdx.x == 1) {
    for (int idx = threadIdx.x; idx < 384 * CIN; idx += 256)
      ipwb[idx] = f2b(ipw[idx]);
  }
  if (blockIdx.x == 2) {
    for (int idx = threadIdx.x; idx < COUT * DIN; idx += 256) {
      float w = opw[idx];
      bf16t hi = f2b(w);
      opwbh[idx] = hi;
      opwbl[idx] = f2b(w - b2f(hi));
    }
  }
  int idx = blockIdx.x * 256 + threadIdx.x;
  int p = idx & (LL - 1);
  int b = idx >> 12;
  float pr[4];
#pragma unroll
  for (int c = 0; c < 4; ++c) pr[c] = prior[((size_t)b * 4 + c) * LL + p];
  float s = sigf(alpha[0]);
  float g2[4];
#pragma unroll
  for (int j = 0; j < 4; ++j) g2[j] = b2[j];
  for (int o = 0; o < 32; ++o) {
    float g = b1[o];
#pragma unroll
    for (int c = 0; c < 4; ++c) g = fmaf(pr[c], w1[o * 4 + c], g);
    g = (g - bnm[o]) * rsqrtf(bnv[o] + 1e-5f) * bnw[o] + bnb[o];
    g = fmaxf(g, 0.0f);
#pragma unroll
    for (int j = 0; j < 4; ++j) g2[j] = fmaf(g, w2[j * 32 + o], g2[j]);
  }
#pragma unroll
  for (int j = 0; j < 4; ++j)
    Wg[((size_t)b * 4 + j) * LL + p] = 1.0f + s * (sigf(g2[j]) - 1.0f);
}

// ---------------------------------------------------------------------------
// FUSED conv+proj: xz bf16 in, xcT bf16 out, projS f32 (scan order).
// ---------------------------------------------------------------------------
__global__ __launch_bounds__(1024) void convproj_k(const bf16t* __restrict__ xz,
                                                   const float* __restrict__ cw,
                                                   const float* __restrict__ cb,
                                                   const float* __restrict__ xpwT,
                                                   bf16t* __restrict__ xcT,
                                                   float* __restrict__ projS) {
  __shared__ float sX[96 * 65];   // 24.96 KB
  __shared__ float4 sP[512];      // 8 KB q-partials
  const int tid = threadIdx.x;
  const int b = blockIdx.y;
  const int h = blockIdx.x;
  const int px = tid & 63;
  const int ku = __builtin_amdgcn_readfirstlane((tid >> 6) & 3);
  const int hf = __builtin_amdgcn_readfirstlane((tid >> 8) & 1);
  const int q  = __builtin_amdgcn_readfirstlane(tid >> 9);
  f32x2 a01 = {0.f, 0.f}, a23 = {0.f, 0.f};

#pragma unroll
  for (int half = 0; half < 2; ++half) {
    for (int idx = tid; idx < 96 * 16; idx += 1024) {
      int ddl = idx >> 4, pq = idx & 15;
      int w0 = pq * 4;
      int dd = half * 96 + ddl;
      const bf16t* base = xz + ((size_t)b * 384 + dd) * LL + h * 64 + w0;
      const float* wp = cw + dd * 9;
      float bv = cb[dd];
      f32x2 s01 = {bv, bv}, s23 = {bv, bv};
#pragma unroll
      for (int dh = -1; dh <= 1; ++dh) {
        int hh = h + dh;
        if (hh < 0 || hh >= HH) continue;
        const bf16t* row = base + dh * 64;
        ushort4 cmu = *(const ushort4*)row;
        float cmx = b2f(cmu.x), cmy = b2f(cmu.y), cmz = b2f(cmu.z), cmw = b2f(cmu.w);
        float lf = (w0 > 0)  ? b2f(row[-1]) : 0.0f;
        float rt = (w0 < 60) ? b2f(row[4])  : 0.0f;
        float c0 = wp[(dh + 1) * 3], c1 = wp[(dh + 1) * 3 + 1], c2 = wp[(dh + 1) * 3 + 2];
        s01 = pkfma((f32x2){lf,  cmx}, (f32x2){c0, c0}, s01);
        s01 = pkfma((f32x2){cmx, cmy}, (f32x2){c1, c1}, s01);
        s01 = pkfma((f32x2){cmy, cmz}, (f32x2){c2, c2}, s01);
        s23 = pkfma((f32x2){cmy, cmz}, (f32x2){c0, c0}, s23);
        s23 = pkfma((f32x2){cmz, cmw}, (f32x2){c1, c1}, s23);
        s23 = pkfma((f32x2){cmw, rt},  (f32x2){c2, c2}, s23);
      }
      float* so = &sX[ddl * 65 + w0];
      float v0 = s01[0], v1 = s01[1], v2 = s23[0], v3 = s23[1];
      so[0] = v0 * sigf(v0);
      so[1] = v1 * sigf(v1);
      so[2] = v2 * sigf(v2);
      so[3] = v3 * sigf(v3);
    }
    __syncthreads();
    for (int idx = tid; idx < 64 * 96; idx += 1024) {
      int pp = idx / 96, ddl = idx % 96;
      xcT[((size_t)b * LL + h * 64 + pp) * DIN + half * 96 + ddl] =
          f2b(sX[ddl * 65 + pp]);
    }
    {
      const int ddl0 = q * 48;
      const float* wp = xpwT + (size_t)ku * (DIN * 8) + (half * 96 + ddl0) * 8 + hf * 4;
#pragma unroll 8
      for (int d48 = 0; d48 < 48; ++d48) {
        float xv = sX[(ddl0 + d48) * 65 + px];
        const float4 w4 = *(const float4*)(wp + d48 * 8);
        const f32x2 xv2 = {xv, xv};
        a01 = pkfma(xv2, (f32x2){w4.x, w4.y}, a01);
        a23 = pkfma(xv2, (f32x2){w4.z, w4.w}, a23);
      }
    }
    __syncthreads();
  }
  const int slot = tid & 511;
  if (q == 1) sP[slot] = make_float4(a01[0], a01[1], a23[0], a23[1]);
  __syncthreads();
  if (q == 0) {
    float4 o = sP[slot];
    float r0 = a01[0] + o.x, r1 = a01[1] + o.y, r2 = a23[0] + o.z, r3 = a23[1] + o.w;
    const int p = h * 64 + px;
    int l;
    if (ku == 0) l = p;
    else if (ku == 1) l = trp(p);
    else if (ku == 2) l = LL - 1 - p;
    else l = LL - 1 - trp(p);
    float* pb = projS + (((size_t)b * KK + ku) * LL + l) * 8 + hf * 4;
    *(float4*)pb = make_float4(r0, r1, r2, r3);
  }
}

// ---------------------------------------------------------------------------
// Scan pass 1 (PAIRED): xcT bf16; carries f32.
// ---------------------------------------------------------------------------
__global__ __launch_bounds__(192) void scan_part_k(const bf16t* __restrict__ xcT,
                                                   const float* __restrict__ projS,
                                                   const float* __restrict__ dtw,
                                                   const float* __restrict__ dtb,
                                                   const float* __restrict__ A_logs,
                                                   float* __restrict__ carrP,
                                                   float* __restrict__ carrH) {
  const int s = blockIdx.x, kp = blockIdx.y, b = blockIdx.z;
  const int d = threadIdx.x;
  const int kA = kp, kB = kp + 2;
  const int s2 = SS - 1 - s;
  const int kdA = kA * DIN + d, kdB = kB * DIN + d;
  float wrA[6], wrB[6];
#pragma unroll
  for (int r = 0; r < 6; ++r) { wrA[r] = dtw[kdA * 6 + r]; wrB[r] = dtw[kdB * 6 + r]; }
  const float biasA = dtb[kdA], biasB = dtb[kdB];
  const float AaA = -__expf(A_logs[kdA]), AaB = -__expf(A_logs[kdB]);
  const int l0 = s * LC;
  const int p0 = pix_of(kA, l0);
  const int dp = pix_of(kA, l0 + 1) - p0;
  const bf16t* xp = xcT + ((size_t)b * LL + p0) * DIN + d;
  const long xstep = (long)dp * DIN;
  const float* prA = projS + (((size_t)b * KK + kA) * LL + l0) * 8;
  const float* prB = projS + (((size_t)b * KK + kB) * LL + s2 * LC + (LC - 1)) * 8;
  float PA = 1.0f, HA = 0.0f, PB = 1.0f, HB = 0.0f;
#pragma unroll 2
  for (int j = 0; j < LC; ++j) {
    float4 a0 = *(const float4*)prA;
    float4 a1 = *(const float4*)(prA + 4);
    prA += 8;
    float4 b0 = *(const float4*)prB;
    float4 b1 = *(const float4*)(prB + 4);
    prB -= 8;
    float xv = b2f(*xp);
    xp += xstep;
    {
      float dtr = biasA;
      dtr = fmaf(a0.x, wrA[0], dtr);
      dtr = fmaf(a0.y, wrA[1], dtr);
      dtr = fmaf(a0.z, wrA[2], dtr);
      dtr = fmaf(a0.w, wrA[3], dtr);
      dtr = fmaf(a1.x, wrA[4], dtr);
      dtr = fmaf(a1.y, wrA[5], dtr);
      float e = exp2fast(fminf(dtr, 80.0f) * LOG2E);
      float u = log2fast(1.0f + e);
      float a = exp2fast(u * AaA);
      float dt = u * LN2;
      HA = fmaf(a, HA, dt * a1.z * xv);
      PA *= a;
    }
    {
      float dtr = biasB;
      dtr = fmaf(b0.x, wrB[0], dtr);
      dtr = fmaf(b0.y, wrB[1], dtr);
      dtr = fmaf(b0.z, wrB[2], dtr);
      dtr = fmaf(b0.w, wrB[3], dtr);
      dtr = fmaf(b1.x, wrB[4], dtr);
      dtr = fmaf(b1.y, wrB[5], dtr);
      float e = exp2fast(fminf(dtr, 80.0f) * LOG2E);
      float u = log2fast(1.0f + e);
      float a = exp2fast(u * AaB);
      float dt = u * LN2;
      HB = fmaf(PB, dt * b1.z * xv, HB);
      PB *= a;
    }
  }
  size_t oA = ((size_t)((b * KK + kA) * SS + s)) * DIN + d;
  size_t oB = ((size_t)((b * KK + kB) * SS + s2)) * DIN + d;
  carrP[oA] = PA;
  carrH[oA] = HA;
  carrP[oB] = PB;
  carrH[oB] = HB;
}

// ---------------------------------------------------------------------------
// Scan pass 2: serial combine of SS carries -> per-segment initial state h0
// ---------------------------------------------------------------------------
__global__ __launch_bounds__(192) void scan_fix_k(const float* __restrict__ carrP,
                                                  const float* __restrict__ carrH,
                                                  float* __restrict__ h0) {
  const int k = blockIdx.x, b = blockIdx.y, d = threadIdx.x;
  size_t base = ((size_t)(b * KK + k)) * SS * DIN + d;
  float h = 0.0f;
#pragma unroll 4
  for (int s = 0; s < SS; ++s) {
    h0[base + (size_t)s * DIN] = h;
    h = fmaf(carrP[base + (size_t)s * DIN], h, carrH[base + (size_t)s * DIN]);
  }
}

// ---------------------------------------------------------------------------
// Scan pass 3: apply + gate + paired merge; xcT bf16 in (reg-cached for dir B),
// ymT/ymT2 bf16 out.
// ---------------------------------------------------------------------------
__global__ __launch_bounds__(192) void scan_apply_k(const bf16t* __restrict__ xcT,
                                                    const float* __restrict__ projS,
                                                    const float* __restrict__ Wg,
                                                    const float* __restrict__ h0,
                                                    const float* __restrict__ dtw,
                                                    const float* __restrict__ dtb,
                                                    const float* __restrict__ A_logs,
                                                    const float* __restrict__ Ds,
                                                    bf16t* __restrict__ ymT,
                                                    bf16t* __restrict__ ymT2) {
  const int s = blockIdx.x, kp = blockIdx.y, b = blockIdx.z;
  const int d = threadIdx.x;
  __shared__ float sAcc[LC * DIN];  // 24 KB, column d thread-private
  float xr[LC];                     // register cache of this segment's xv
  {
    const int k = kp, kd = k * DIN + d;
    float wr[6];
#pragma unroll
    for (int r = 0; r < 6; ++r) wr[r] = dtw[kd * 6 + r];
    const float bias = dtb[kd];
    const float Aa = -__expf(A_logs[kd]);
    const float Dv = Ds[kd];
    const int l0 = s * LC;
    const int p0 = pix_of(k, l0);
    const int dp = pix_of(k, l0 + 1) - p0;
    const bf16t* xp = xcT + ((size_t)b * LL + p0) * DIN + d;
    const long xstep = (long)dp * DIN;
    const float* pr = projS + (((size_t)b * KK + k) * LL + l0) * 8;
    const float* wg = Wg + ((size_t)b * KK + k) * LL + l0;
    float h = h0[((size_t)((b * KK + k) * SS + s)) * DIN + d];
#pragma unroll
    for (int j = 0; j < LC; ++j) {
      float4 q0 = *(const float4*)pr;
      float4 q1 = *(const float4*)(pr + 4);
      pr += 8;
      float xv = b2f(*xp);
      xp += xstep;
      xr[j] = xv;
      float dtr = bias;
      dtr = fmaf(q0.x, wr[0], dtr);
      dtr = fmaf(q0.y, wr[1], dtr);
      dtr = fmaf(q0.z, wr[2], dtr);
      dtr = fmaf(q0.w, wr[3], dtr);
      dtr = fmaf(q1.x, wr[4], dtr);
      dtr = fmaf(q1.y, wr[5], dtr);
      float e = exp2fast(fminf(dtr, 80.0f) * LOG2E);
      float u = log2fast(1.0f + e);
      float a = exp2fast(u * Aa);
      float dt = u * LN2;
      h = fmaf(a, h, dt * q1.z * xv);
      sAcc[j * DIN + d] = fmaf(h, q1.w, Dv * xv) * wg[j];
    }
  }
  {
    const int k = kp + 2, kd = k * DIN + d;
    const int s2 = SS - 1 - s;
    float wr[6];
#pragma unroll
    for (int r = 0; r < 6; ++r) wr[r] = dtw[kd * 6 + r];
    const float bias = dtb[kd];
    const float Aa = -__expf(A_logs[kd]);
    const float Dv = Ds[kd];
    const int l0 = s2 * LC;
    const float* pr = projS + (((size_t)b * KK + k) * LL + l0) * 8;
    const float* wg = Wg + ((size_t)b * KK + k) * LL + l0;
    float h = h0[((size_t)((b * KK + k) * SS + s2)) * DIN + d];
#pragma unroll
    for (int j = 0; j < LC; ++j) {
      float4 q0 = *(const float4*)pr;
      float4 q1 = *(const float4*)(pr + 4);
      pr += 8;
      float xv = xr[LC - 1 - j];   // same pixels, reversed (static index)
      float dtr = bias;
      dtr = fmaf(q0.x, wr[0], dtr);
      dtr = fmaf(q0.y, wr[1], dtr);
      dtr = fmaf(q0.z, wr[2], dtr);
      dtr = fmaf(q0.w, wr[3], dtr);
      dtr = fmaf(q1.x, wr[4], dtr);
      dtr = fmaf(q1.y, wr[5], dtr);
      float e = exp2fast(fminf(dtr, 80.0f) * LOG2E);
      float u = log2fast(1.0f + e);
      float a = exp2fast(u * Aa);
      float dt = u * LN2;
      h = fmaf(a, h, dt * q1.z * xv);
      float y = fmaf(h, q1.w, Dv * xv) * wg[j];
      sAcc[(LC - 1 - j) * DIN + d] += y;
    }
  }
  bf16t* dst;
  if (kp == 0)
    dst = ymT + (size_t)b * (384 * (size_t)LL) + (size_t)(s * LC) * DIN + d;  // xz overlay
  else
    dst = ymT2 + ((size_t)b * LL + s * LC) * DIN + d;
#pragma unroll 4
  for (int j = 0; j < LC; ++j) dst[(size_t)j * DIN] = f2b(sAcc[j * DIN + d]);
}

// ---------------------------------------------------------------------------
extern "C" void kernel_launch(void* const* d_in, const int* in_sizes, int n_in,
                              void* d_out, int out_size, void* d_ws, size_t ws_size,
                              hipStream_t stream) {
  const float* x      = (const float*)d_in[0];
  const float* prior  = (const float*)d_in[1];
  const float* alpha  = (const float*)d_in[2];
  const float* ipw    = (const float*)d_in[3];
  const float* cw     = (const float*)d_in[4];
  const float* cb     = (const float*)d_in[5];
  const float* xpw    = (const float*)d_in[6];
  const float* dtw    = (const float*)d_in[7];
  const float* dtb    = (const float*)d_in[8];
  const float* A_logs = (const float*)d_in[9];
  const float* Ds     = (const float*)d_in[10];
  const float* onw    = (const float*)d_in[11];
  const float* onb    = (const float*)d_in[12];
  const float* opw    = (const float*)d_in[13];
  const float* w1     = (const float*)d_in[14];
  const float* b1     = (const float*)d_in[15];
  const float* bnw    = (const float*)d_in[16];
  const float* bnb    = (const float*)d_in[17];
  const float* bnm    = (const float*)d_in[18];
  const float* bnv    = (const float*)d_in[19];
  const float* w2     = (const float*)d_in[20];
  const float* b2     = (const float*)d_in[21];
  float* out = (float*)d_out;

  char* ws = (char*)d_ws;
  // bf16 intermediates; footprint ends at 64,659,456 B.
  bf16t* xz    = (bf16t*)(ws);              // [B,384,L] bf16  25.2 MB
  bf16t* xcT   = (bf16t*)(ws + 25165824);   // [B,L,192] bf16  12.6 MB
  bf16t* ymT2  = (bf16t*)(ws + 37748736);   // [B,L,192] bf16  12.6 MB
  float* projS = (float*)(ws + 50331648);   // [B,K,L,8] f32    4.2 MB
  float* Wgb   = (float*)(ws + 54525952);   // [B,4,L]          0.5 MB
  float* carrP = (float*)(ws + 55050240);   // [B,K,SS,192]     3.0 MB
  float* carrH = (float*)(ws + 58195968);   // [B,K,SS,192]     3.0 MB
  float* h0b   = (float*)(ws + 61341696);   // [B,K,SS,192]     3.0 MB
  float* xpwT  = (float*)(ws + 64487424);   // [K,DIN,8]       24.6 KB
  bf16t* ipwb  = (bf16t*)(ws + 64512000);   // [384,96] bf16   73.7 KB
  bf16t* opwbh = (bf16t*)(ws + 64585728);   // [96,192] bf16   36.9 KB
  bf16t* opwbl = (bf16t*)(ws + 64622592);   // [96,192] bf16   36.9 KB (ends 64659456)
  bf16t* ymT   = xz;   // overlay: x_ssm half of xz (dead after convproj)

  // 1) prior -> direction gates (+ weight preps in blocks 0,1,2)
  p2w_k<<<(BB * LL) / 256, 256, 0, stream>>>(prior, alpha, w1, b1, bnw, bnb, bnm,
                                             bnv, w2, b2, xpw, ipw, opw, xpwT,
                                             ipwb, opwbh, opwbl, Wgb);
  // 2) in_proj via MFMA bf16 -> xz bf16
  gemm_in_mfma_k<<<dim3(LL / 32, 1, BB), 256, 0, stream>>>(x, ipwb, xz);
  // 3) fused dwconv+SiLU + x_proj(scan-order) + transpose
  convproj_k<<<dim3(HH, BB), 1024, 0, stream>>>(xz, cw, cb, xpwT, xcT, projS);
  // 4) scan: paired segment carries
  scan_part_k<<<dim3(SS, 2, BB), 192, 0, stream>>>(xcT, projS, dtw, dtb, A_logs,
                                                   carrP, carrH);
  // 5) scan: serial carry combine
  scan_fix_k<<<dim3(KK, BB), 192, 0, stream>>>(carrP, carrH, h0b);
  // 6) scan: apply + gate + paired merge (ymT overlaid on xz x_ssm half)
  scan_apply_k<<<dim3(SS, 2, BB), 192, 0, stream>>>(xcT, projS, Wgb, h0b, dtw, dtb,
                                                    A_logs, Ds, ymT, ymT2);
  // 7) fused LayerNorm*silu(z) + out_proj MFMA -> out f32
  ln_gemm_out_k<<<dim3(LL / 64, 1, BB), 384, 0, stream>>>(ymT, ymT2, xz, onw, onb,
                                                          opwbh, opwbl, out);
}